// Round 11
// baseline (290.674 us; speedup 1.0000x reference)
//
#include <hip/hip_runtime.h>

#define HH 192
#define WW 192
#define CC 64
#define BB 8
#define SH 8
#define HWSZ (HH*WW)
#define TAU 0.1f

// ======== Kernel A0: transpose w1 [sh][c][9] -> wt [c][sh][9] (contiguous per channel) ========
__global__ __launch_bounds__(256) void transpose_w1_kernel(
    const float* __restrict__ w1, float* __restrict__ wt)
{
    int i = blockIdx.x * 256 + threadIdx.x;          // 0..4607
    if (i < CC * SH * 9) {
        int c  = i / (SH * 9);
        int r  = i - c * (SH * 9);
        int sh = r / 9;
        int k  = r - sh * 9;
        wt[i] = w1[((size_t)sh * CC + c) * 9 + k];
    }
}

// ======== Kernel A: direct conv3x3 (64->8, SAME) + exact GELU, sh-split x2 ========
// No LDS/barriers. Each block computes 4 of 8 output channels for a 16x16 tile:
// per channel 9 imm-offset loads + 36 FMA. 2304 blocks -> ~9 waves/SIMD for
// latency hiding. Weights from wt[c][8][9] (contiguous -> s_load_dwordx16).
__global__ __launch_bounds__(256) void conv1_gelu_kernel(
    const float* __restrict__ x, const float* __restrict__ wt, float* __restrict__ h)
{
    // swizzle: XCD = li&7 = batch; for fixed b, (tile,half) pairs adjacent ->
    // both halves of a tile co-resident on one XCD (shared x reads hit L2).
    const int li   = blockIdx.x;
    const int b    = li & 7;
    const int r    = li >> 3;            // 0..287
    const int half = r & 1;
    const int m    = r >> 1;             // 0..143
    const int tyb  = m / 12, txb = m - tyb * 12;

    const int t  = threadIdx.x;
    const int tx = t & 15, ty = t >> 4;
    const int xo = txb * 16 + tx;
    const int yo = tyb * 16 + ty;
    const int pix = yo * WW + xo;

    const float* xb = x + (size_t)b * CC * HWSZ;
    const int sh0 = half * 4;

    float acc[4];
#pragma unroll
    for (int j = 0; j < 4; j++) acc[j] = 0.f;

    const bool border = (txb == 0) | (txb == 11) | (tyb == 0) | (tyb == 11);

    if (!border) {
        const float* p = xb + pix;
        for (int c = 0; c < CC; c++) {
            const float* pc = p + (size_t)c * HWSZ;
            float v[9];
            v[0] = pc[-WW - 1]; v[1] = pc[-WW]; v[2] = pc[-WW + 1];
            v[3] = pc[-1];      v[4] = pc[0];   v[5] = pc[1];
            v[6] = pc[WW - 1];  v[7] = pc[WW];  v[8] = pc[WW + 1];
            const float* ws = wt + c * (SH * 9) + sh0 * 9;   // uniform, contiguous 144B
#pragma unroll
            for (int j = 0; j < 4; j++) {
                float a = acc[j];
#pragma unroll
                for (int k = 0; k < 9; k++) a = fmaf(v[k], ws[j * 9 + k], a);
                acc[j] = a;
            }
        }
    } else {
        const int ym1 = max(yo - 1, 0), yp1 = min(yo + 1, HH - 1);
        const int xm1 = max(xo - 1, 0), xp1 = min(xo + 1, WW - 1);
        const int r0 = ym1 * WW, r1 = yo * WW, r2 = yp1 * WW;
        const bool vy0 = yo > 0, vy2 = yo < HH - 1, vx0 = xo > 0, vx2 = xo < WW - 1;
        int  o[9]  = {r0 + xm1, r0 + xo, r0 + xp1,
                      r1 + xm1, r1 + xo, r1 + xp1,
                      r2 + xm1, r2 + xo, r2 + xp1};
        bool mk[9] = {vy0 && vx0, vy0, vy0 && vx2,
                      vx0,        true, vx2,
                      vy2 && vx0, vy2, vy2 && vx2};
        for (int c = 0; c < CC; c++) {
            const float* pc = xb + (size_t)c * HWSZ;
            float v[9];
#pragma unroll
            for (int k = 0; k < 9; k++) v[k] = pc[o[k]];
#pragma unroll
            for (int k = 0; k < 9; k++) if (!mk[k]) v[k] = 0.f;
            const float* ws = wt + c * (SH * 9) + sh0 * 9;
#pragma unroll
            for (int j = 0; j < 4; j++) {
                float a = acc[j];
#pragma unroll
                for (int k = 0; k < 9; k++) a = fmaf(v[k], ws[j * 9 + k], a);
                acc[j] = a;
            }
        }
    }

    // epilogue: exact GELU, store one float4 half of h[b][pix][8]
    float4 o0;
    o0.x = 0.5f * acc[0] * (1.f + erff(acc[0] * 0.70710678118654752f));
    o0.y = 0.5f * acc[1] * (1.f + erff(acc[1] * 0.70710678118654752f));
    o0.z = 0.5f * acc[2] * (1.f + erff(acc[2] * 0.70710678118654752f));
    o0.w = 0.5f * acc[3] * (1.f + erff(acc[3] * 0.70710678118654752f));
    *(float4*)&h[((size_t)b * HWSZ + pix) * SH + sh0] = o0;
}

// ======== Kernel B: 1x1 conv coeffs + softplus/clip + 4 bilinear samples ========
#define TILES_PER_PLANE 144   // 12x12 tiles of 16x16
#define NPLANES (BB*CC)       // 512

__global__ __launch_bounds__(256) void coeff_sample_kernel(
    const float* __restrict__ x, const float* __restrict__ hbuf,
    const float* __restrict__ w2, const float* __restrict__ b2,
    const float* __restrict__ log_scale, float* __restrict__ out)
{
    // XCD-aware swizzle: all 144 tiles of one (b,c) plane land on one XCD.
    const int li = blockIdx.x;
    const int rr = li & 7;
    const int m  = li >> 3;
    const int q  = m / TILES_PER_PLANE;
    const int tt = m - q * TILES_PER_PLANE;
    const int bc = (q << 3) | rr;          // plane id: b*64 + c
    const int tyb = tt / 12, txb = tt - tyb * 12;

    const int t  = threadIdx.x;
    const int tx = t & 15;
    const int ty = t >> 4;
    const int xo = txb * 16 + tx;
    const int y  = tyb * 16 + ty;
    const int c  = bc & 63;
    const int pix = y * WW + xo;

    // h interleaved [b][pix][8]: two float4 loads
    const float4* hp4 = (const float4*)&hbuf[((size_t)(bc >> 6) * HWSZ + pix) * SH];
    float4 h0 = hp4[0], h1 = hp4[1];
    float hk[SH] = {h0.x, h0.y, h0.z, h0.w, h1.x, h1.y, h1.z, h1.w};

    const int c4 = c * 4;
    float coeff[4];
#pragma unroll
    for (int j = 0; j < 4; j++) {
        const float* wr = w2 + (size_t)(c4 + j) * SH;  // uniform per block
        float s = b2[c4 + j];
#pragma unroll
        for (int k = 0; k < SH; k++) s = fmaf(hk[k], wr[k], s);
        coeff[j] = s;
    }

    // softplus (stable): max(z,0) + log(1+exp(-|z|))
    float z  = coeff[0];
    float a  = fmaxf(z, 0.f) + __logf(1.f + __expf(-fabsf(z)));
    float s  = __builtin_amdgcn_sqrtf(fmaf(a, TAU, 1e-8f));
    float dx = coeff[1] * TAU;
    float dy = coeff[2] * TAU;
    float cc = __builtin_amdgcn_fmed3f(coeff[3], -5.f, 5.f);

    const float* img = x + (size_t)bc * HWSZ;
    const float px0 = (float)xo + dx * 95.5f;   // (W-1)/2 = 95.5
    const float py0 = (float)y  + dy * 95.5f;
    const float sp  = s * 95.5f;

    float u;
    {   // u_px + u_nx: shared y state, pair-loaded rows
        float pyc = __builtin_amdgcn_fmed3f(py0, 0.f, 191.f);
        float y0f = floorf(pyc);
        float wy  = pyc - y0f;
        int y0 = (int)y0f;
        unsigned r0 = (unsigned)(y0 * WW);
        unsigned r1 = r0 + ((y0 < HH - 1) ? WW : 0);
        u = 0.f;
#pragma unroll
        for (int sgn = 0; sgn < 2; sgn++) {
            float px  = sgn ? (px0 - sp) : (px0 + sp);
            float pxc = __builtin_amdgcn_fmed3f(px, 0.f, 191.f);
            float x0f = floorf(pxc);
            float wx  = pxc - x0f;
            int  x0 = (int)x0f;
            bool hi = x0 > WW - 2;                     // x0 == 191
            unsigned xc = (unsigned)min(x0, WW - 2);
            float2 t0 = *(const float2*)(img + (r0 + xc));
            float2 t1 = *(const float2*)(img + (r1 + xc));
            float v00 = hi ? t0.y : t0.x;
            float v10 = hi ? t1.y : t1.x;
            float top = fmaf(wx, t0.y - v00, v00);
            float bot = fmaf(wx, t1.y - v10, v10);
            u += fmaf(wy, bot - top, top);
        }
    }
    {   // u_py + u_ny: shared x state (pair columns), per-sample y state
        float pxc = __builtin_amdgcn_fmed3f(px0, 0.f, 191.f);
        float x0f = floorf(pxc);
        float wx  = pxc - x0f;
        int  x0 = (int)x0f;
        bool hi = x0 > WW - 2;
        unsigned xc = (unsigned)min(x0, WW - 2);
#pragma unroll
        for (int sgn = 0; sgn < 2; sgn++) {
            float py  = sgn ? (py0 - sp) : (py0 + sp);
            float pyc = __builtin_amdgcn_fmed3f(py, 0.f, 191.f);
            float y0f = floorf(pyc);
            float wy  = pyc - y0f;
            int y0 = (int)y0f;
            unsigned r0 = (unsigned)(y0 * WW);
            unsigned r1 = r0 + ((y0 < HH - 1) ? WW : 0);
            float2 t0 = *(const float2*)(img + (r0 + xc));
            float2 t1 = *(const float2*)(img + (r1 + xc));
            float v00 = hi ? t0.y : t0.x;
            float v10 = hi ? t1.y : t1.x;
            float top = fmaf(wx, t0.y - v00, v00);
            float bot = fmaf(wx, t1.y - v10, v10);
            u += fmaf(wy, bot - top, top);
        }
    }

    float xv    = img[(unsigned)pix];
    float scale = __expf(log_scale[0]);
    out[(size_t)bc * HWSZ + pix] = scale * fmaf(0.25f, u, TAU * cc * xv);
}

extern "C" void kernel_launch(void* const* d_in, const int* in_sizes, int n_in,
                              void* d_out, int out_size, void* d_ws, size_t ws_size,
                              hipStream_t stream)
{
    const float* x   = (const float*)d_in[0];
    const float* w1  = (const float*)d_in[1];
    const float* w2  = (const float*)d_in[2];
    const float* b2  = (const float*)d_in[3];
    const float* ls  = (const float*)d_in[4];
    float* out = (float*)d_out;
    float* h   = (float*)d_ws;        // B*HW*8 floats = 9.4 MB, interleaved [b][pix][8]

    // wt lives in the tail of d_out: read by conv, overwritten later by coeff_sample
    float* wt = out + (size_t)out_size - CC * SH * 9;

    dim3 blk(256);
    transpose_w1_kernel<<<dim3((CC * SH * 9 + 255) / 256), blk, 0, stream>>>(w1, wt);

    conv1_gelu_kernel<<<dim3(12 * 12 * BB * 2), blk, 0, stream>>>(x, wt, h);

    coeff_sample_kernel<<<dim3(NPLANES * TILES_PER_PLANE), blk, 0, stream>>>(
        x, h, w2, b2, ls, out);
}

// Round 15
// 273.041 us; speedup vs baseline: 1.0646x; 1.0646x over previous
//
#include <hip/hip_runtime.h>

#define HH 192
#define WW 192
#define CC 64
#define BB 8
#define SH 8
#define HWSZ (HH*WW)
#define TAU 0.1f

// ======== Kernel A0: transpose w1 [sh][c][9] -> wt [c][sh][9] (contiguous per channel) ========
__global__ __launch_bounds__(256) void transpose_w1_kernel(
    const float* __restrict__ w1, float* __restrict__ wt)
{
    int i = blockIdx.x * 256 + threadIdx.x;          // 0..4607
    if (i < CC * SH * 9) {
        int c  = i / (SH * 9);
        int r  = i - c * (SH * 9);
        int sh = r / 9;
        int k  = r - sh * 9;
        wt[i] = w1[((size_t)sh * CC + c) * 9 + k];
    }
}

// ======== Fused kernel: conv3x3+GELU (h in registers) -> 64x coeffs+sampling ========
// One block per 16x16 tile per batch. Phase 1: 64-channel conv -> hk[8] regs.
// Phase 2: loop c=0..63: w2/b2 scalar loads, coeffs, softplus, 4 bilinear
// samples from x[b,c], write out[b,c]. No LDS, no barriers, no h memory.
__global__ __launch_bounds__(256) void fused_kernel(
    const float* __restrict__ x, const float* __restrict__ wt,
    const float* __restrict__ w2, const float* __restrict__ b2,
    const float* __restrict__ log_scale, float* __restrict__ out)
{
    // Batch-per-XCD swizzle: XCD = li&7 = batch; tiles raster-ordered per batch.
    const int li  = blockIdx.x;
    const int b   = li & 7;
    const int m   = li >> 3;             // 0..143
    const int tyb = m / 12, txb = m - tyb * 12;

    const int t  = threadIdx.x;
    const int tx = t & 15, ty = t >> 4;
    const int xo = txb * 16 + tx;
    const int yo = tyb * 16 + ty;
    const int pix = yo * WW + xo;

    const float* xb = x + (size_t)b * CC * HWSZ;

    // ---------- Phase 1: conv3x3 over 64 channels, 8 outputs in registers ----------
    float acc[SH];
#pragma unroll
    for (int sh = 0; sh < SH; sh++) acc[sh] = 0.f;

    const bool border = (txb == 0) | (txb == 11) | (tyb == 0) | (tyb == 11);

    if (!border) {
        const float* p = xb + pix;
        for (int c = 0; c < CC; c++) {
            const float* pc = p + (size_t)c * HWSZ;
            float v[9];
            v[0] = pc[-WW - 1]; v[1] = pc[-WW]; v[2] = pc[-WW + 1];
            v[3] = pc[-1];      v[4] = pc[0];   v[5] = pc[1];
            v[6] = pc[WW - 1];  v[7] = pc[WW];  v[8] = pc[WW + 1];
            const float* ws = wt + c * (SH * 9);    // uniform, contiguous 288B
#pragma unroll
            for (int sh = 0; sh < SH; sh++) {
                float a = acc[sh];
#pragma unroll
                for (int k = 0; k < 9; k++) a = fmaf(v[k], ws[sh * 9 + k], a);
                acc[sh] = a;
            }
        }
    } else {
        const int ym1 = max(yo - 1, 0), yp1 = min(yo + 1, HH - 1);
        const int xm1 = max(xo - 1, 0), xp1 = min(xo + 1, WW - 1);
        const int r0 = ym1 * WW, r1 = yo * WW, r2 = yp1 * WW;
        const bool vy0 = yo > 0, vy2 = yo < HH - 1, vx0 = xo > 0, vx2 = xo < WW - 1;
        int  o[9]  = {r0 + xm1, r0 + xo, r0 + xp1,
                      r1 + xm1, r1 + xo, r1 + xp1,
                      r2 + xm1, r2 + xo, r2 + xp1};
        bool mk[9] = {vy0 && vx0, vy0, vy0 && vx2,
                      vx0,        true, vx2,
                      vy2 && vx0, vy2, vy2 && vx2};
        for (int c = 0; c < CC; c++) {
            const float* pc = xb + (size_t)c * HWSZ;
            float v[9];
#pragma unroll
            for (int k = 0; k < 9; k++) v[k] = pc[o[k]];
#pragma unroll
            for (int k = 0; k < 9; k++) if (!mk[k]) v[k] = 0.f;
            const float* ws = wt + c * (SH * 9);
#pragma unroll
            for (int sh = 0; sh < SH; sh++) {
                float a = acc[sh];
#pragma unroll
                for (int k = 0; k < 9; k++) a = fmaf(v[k], ws[sh * 9 + k], a);
                acc[sh] = a;
            }
        }
    }

    float hk[SH];
#pragma unroll
    for (int sh = 0; sh < SH; sh++)
        hk[sh] = 0.5f * acc[sh] * (1.f + erff(acc[sh] * 0.70710678118654752f));

    // ---------- Phase 2: per-channel coeffs + 4 bilinear samples ----------
    const float scale = __expf(log_scale[0]);
    const float xf = (float)xo, yf = (float)yo;
    float* outp = out + (size_t)b * CC * HWSZ + pix;

    for (int c = 0; c < CC; c++) {
        const float* w2c = w2 + c * 32;      // uniform, 32 contiguous floats
        const float* b2c = b2 + c * 4;
        float coeff[4];
#pragma unroll
        for (int j = 0; j < 4; j++) {
            float s = b2c[j];
#pragma unroll
            for (int k = 0; k < SH; k++) s = fmaf(hk[k], w2c[j * 8 + k], s);
            coeff[j] = s;
        }

        // softplus (stable): max(z,0) + log(1+exp(-|z|))
        float z  = coeff[0];
        float a  = fmaxf(z, 0.f) + __logf(1.f + __expf(-fabsf(z)));
        float s  = __builtin_amdgcn_sqrtf(fmaf(a, TAU, 1e-8f));
        float dx = coeff[1] * TAU;
        float dy = coeff[2] * TAU;
        float cc = __builtin_amdgcn_fmed3f(coeff[3], -5.f, 5.f);

        const float* img = xb + (size_t)c * HWSZ;
        const float px0 = xf + dx * 95.5f;   // (W-1)/2 = 95.5
        const float py0 = yf + dy * 95.5f;
        const float sp  = s * 95.5f;

        float u;
        {   // u_px + u_nx: shared y state, pair-loaded rows
            float pyc = __builtin_amdgcn_fmed3f(py0, 0.f, 191.f);
            float y0f = floorf(pyc);
            float wy  = pyc - y0f;
            int y0 = (int)y0f;
            unsigned r0 = (unsigned)(y0 * WW);
            unsigned r1 = r0 + ((y0 < HH - 1) ? WW : 0);
            u = 0.f;
#pragma unroll
            for (int sgn = 0; sgn < 2; sgn++) {
                float px  = sgn ? (px0 - sp) : (px0 + sp);
                float pxc = __builtin_amdgcn_fmed3f(px, 0.f, 191.f);
                float x0f = floorf(pxc);
                float wx  = pxc - x0f;
                int  x0 = (int)x0f;
                bool hi = x0 > WW - 2;                     // x0 == 191
                unsigned xc = (unsigned)min(x0, WW - 2);
                float2 t0 = *(const float2*)(img + (r0 + xc));
                float2 t1 = *(const float2*)(img + (r1 + xc));
                float v00 = hi ? t0.y : t0.x;
                float v10 = hi ? t1.y : t1.x;
                float top = fmaf(wx, t0.y - v00, v00);
                float bot = fmaf(wx, t1.y - v10, v10);
                u += fmaf(wy, bot - top, top);
            }
        }
        {   // u_py + u_ny: shared x state (pair columns), per-sample y state
            float pxc = __builtin_amdgcn_fmed3f(px0, 0.f, 191.f);
            float x0f = floorf(pxc);
            float wx  = pxc - x0f;
            int  x0 = (int)x0f;
            bool hi = x0 > WW - 2;
            unsigned xc = (unsigned)min(x0, WW - 2);
#pragma unroll
            for (int sgn = 0; sgn < 2; sgn++) {
                float py  = sgn ? (py0 - sp) : (py0 + sp);
                float pyc = __builtin_amdgcn_fmed3f(py, 0.f, 191.f);
                float y0f = floorf(pyc);
                float wy  = pyc - y0f;
                int y0 = (int)y0f;
                unsigned r0 = (unsigned)(y0 * WW);
                unsigned r1 = r0 + ((y0 < HH - 1) ? WW : 0);
                float2 t0 = *(const float2*)(img + (r0 + xc));
                float2 t1 = *(const float2*)(img + (r1 + xc));
                float v00 = hi ? t0.y : t0.x;
                float v10 = hi ? t1.y : t1.x;
                float top = fmaf(wx, t0.y - v00, v00);
                float bot = fmaf(wx, t1.y - v10, v10);
                u += fmaf(wy, bot - top, top);
            }
        }

        float xv = img[(unsigned)pix];
        outp[(size_t)c * HWSZ] = scale * fmaf(0.25f, u, TAU * cc * xv);
    }
}

extern "C" void kernel_launch(void* const* d_in, const int* in_sizes, int n_in,
                              void* d_out, int out_size, void* d_ws, size_t ws_size,
                              hipStream_t stream)
{
    const float* x   = (const float*)d_in[0];
    const float* w1  = (const float*)d_in[1];
    const float* w2  = (const float*)d_in[2];
    const float* b2  = (const float*)d_in[3];
    const float* ls  = (const float*)d_in[4];
    float* out = (float*)d_out;
    float* wt  = (float*)d_ws;        // 4608 floats = 18.4 KB scratch

    dim3 blk(256);
    transpose_w1_kernel<<<dim3((CC * SH * 9 + 255) / 256), blk, 0, stream>>>(w1, wt);

    fused_kernel<<<dim3(12 * 12 * BB), blk, 0, stream>>>(x, wt, w2, b2, ls, out);
}